// Round 4
// baseline (370.010 us; speedup 1.0000x reference)
//
#include <hip/hip_runtime.h>
#include <hip/hip_bf16.h>

#define T_TOK 2048
#define HID 1024
#define FFNDIM 2048
#define NEXP 8

typedef __attribute__((ext_vector_type(8))) short short8;
typedef __attribute__((ext_vector_type(4))) float f32x4;

__device__ inline unsigned short f2bf(float f) {
  union { float f; unsigned int u; } v; v.f = f;
  unsigned int u = v.u;
  unsigned int r = (u + 0x7fffu + ((u >> 16) & 1u)) >> 16;
  return (unsigned short)r;
}

__device__ inline void gload_lds16(const void* g, void* l) {
  __builtin_amdgcn_global_load_lds((const __attribute__((address_space(1))) void*)g,
                                   (__attribute__((address_space(3))) void*)l, 16, 0, 0);
}

// ---------------- router: 1 wave per token ----------------
__global__ __launch_bounds__(256) void router_kernel(
    const float* __restrict__ x, const float* __restrict__ gw,
    int* __restrict__ counts, int* __restrict__ top_i, float* __restrict__ top_w) {
  int lane = threadIdx.x & 63;
  int t = blockIdx.x * 4 + (threadIdx.x >> 6);
  if (t >= T_TOK) return;
  float xv[16];
#pragma unroll
  for (int i = 0; i < 16; ++i) xv[i] = x[(size_t)t * HID + i * 64 + lane];
  float logit[NEXP];
#pragma unroll
  for (int e = 0; e < NEXP; ++e) {
    float s = 0.f;
#pragma unroll
    for (int i = 0; i < 16; ++i) s += xv[i] * gw[e * HID + i * 64 + lane];
#pragma unroll
    for (int off = 32; off > 0; off >>= 1) s += __shfl_xor(s, off);
    logit[e] = s;
  }
  if (lane == 0) {
    float mx = logit[0];
#pragma unroll
    for (int e = 1; e < NEXP; ++e) mx = fmaxf(mx, logit[e]);
    float p[NEXP]; float sum = 0.f;
#pragma unroll
    for (int e = 0; e < NEXP; ++e) { p[e] = expf(logit[e] - mx); sum += p[e]; }
#pragma unroll
    for (int e = 0; e < NEXP; ++e) p[e] /= sum;
    int i0 = 0;
#pragma unroll
    for (int e = 1; e < NEXP; ++e) if (p[e] > p[i0]) i0 = e;
    int i1 = (i0 == 0) ? 1 : 0;
#pragma unroll
    for (int e = 0; e < NEXP; ++e) if (e != i0 && p[e] > p[i1]) i1 = e;
    float w0 = p[i0], w1v = p[i1];
    float s2 = w0 + w1v;
    w0 /= s2; w1v /= s2;
    top_i[t * 2 + 0] = i0; top_i[t * 2 + 1] = i1;
    top_w[t * 2 + 0] = w0; top_w[t * 2 + 1] = w1v;
    atomicAdd(&counts[i0], 1);
    atomicAdd(&counts[i1], 1);
  }
}

__global__ void offsets_kernel(const int* __restrict__ counts, int* __restrict__ offsets) {
  if (threadIdx.x == 0 && blockIdx.x == 0) {
    int s = 0;
    for (int e = 0; e < NEXP; ++e) { offsets[e] = s; s += counts[e]; }
    offsets[NEXP] = s;
  }
}

__global__ __launch_bounds__(256) void scatter_kernel(
    const int* __restrict__ top_i, const float* __restrict__ top_w,
    const int* __restrict__ offsets, int* __restrict__ cursor,
    int* __restrict__ row_tok, float* __restrict__ row_w) {
  int t = blockIdx.x * 256 + threadIdx.x;
  if (t >= T_TOK) return;
#pragma unroll
  for (int k = 0; k < 2; ++k) {
    int e = top_i[t * 2 + k];
    int p = atomicAdd(&cursor[e], 1);
    int idx = offsets[e] + p;
    row_tok[idx] = t;
    row_w[idx] = top_w[t * 2 + k];
  }
}

__global__ __launch_bounds__(256) void gather_kernel(
    const float* __restrict__ x, const int* __restrict__ row_tok,
    unsigned short* __restrict__ Xg) {
  int r = blockIdx.x;
  int t = row_tok[r];
  int c = threadIdx.x * 4;
  float4 v = *reinterpret_cast<const float4*>(x + (size_t)t * HID + c);
  ushort4 o;
  o.x = f2bf(v.x); o.y = f2bf(v.y); o.z = f2bf(v.z); o.w = f2bf(v.w);
  *reinterpret_cast<ushort4*>(Xg + (size_t)r * HID + c) = o;
}

// ---------------- fp32 -> bf16 conversion for all 3 weight tensors ----------------
__global__ __launch_bounds__(256) void w2bf3_kernel(
    const float4* __restrict__ s0, const float4* __restrict__ s1, const float4* __restrict__ s2,
    ushort4* __restrict__ d0, ushort4* __restrict__ d1, ushort4* __restrict__ d2, int n4) {
  int i = blockIdx.x * 256 + threadIdx.x;
  if (i >= n4) return;
  const float4* s = (blockIdx.y == 0) ? s0 : (blockIdx.y == 1) ? s1 : s2;
  ushort4* d = (blockIdx.y == 0) ? d0 : (blockIdx.y == 1) ? d1 : d2;
  float4 v = s[i];
  ushort4 o;
  o.x = f2bf(v.x); o.y = f2bf(v.y); o.z = f2bf(v.z); o.w = f2bf(v.w);
  d[i] = o;
}

// ======== GEMM1: 256 rows x 128 ffn-cols x {w1,w3}; 8 waves; BK=32; 2-phase ========
// B tile rows r=0..255: wn=r>>6, s=r&63; s<32 -> w1, else w3; wrow = nt*128+wn*32+(s&31).
// Wave (wm, wn): out rows wm*128+mf*16.., cols: nf 0..1 -> w1 col wn*32+nf*16+fr,
//                                          nf 2..3 -> w3 col wn*32+(nf-2)*16+fr.
__global__ __launch_bounds__(512, 2) void gemm1_256(
    const unsigned short* __restrict__ Xg,
    const unsigned short* __restrict__ Wb1, const unsigned short* __restrict__ Wb3,
    const int* __restrict__ counts, const int* __restrict__ offsets,
    unsigned short* __restrict__ hbuf) {
  int e = blockIdx.z;
  int cnt = counts[e];
  int nt = blockIdx.x, mt = blockIdx.y;
  if (cnt == 0 || mt * 256 >= cnt) return;
  int off = offsets[e];

  __shared__ alignas(16) unsigned short sA[2][256 * 32];
  __shared__ alignas(16) unsigned short sB[2][256 * 32];

  int tid = threadIdx.x;
  int lane = tid & 63, wid = tid >> 6;
  int wm = wid >> 2, wn = wid & 3;            // 2 x 4 waves
  int fr = lane & 15, fq = lane >> 4;

  const unsigned short* b1B = Wb1 + (size_t)e * FFNDIM * HID;
  const unsigned short* b3B = Wb3 + (size_t)e * FFNDIM * HID;
  int ntb = nt * 128;

  f32x4 acc[8][4];
#pragma unroll
  for (int mf = 0; mf < 8; ++mf)
#pragma unroll
    for (int nf = 0; nf < 4; ++nf) acc[mf][nf] = (f32x4){0.f, 0.f, 0.f, 0.f};

#define STAGE1(P, K0)                                                        \
  do {                                                                       \
    _Pragma("unroll")                                                        \
    for (int j = 0; j < 2; ++j) {                                            \
      int r = j * 128 + (tid >> 2);                                          \
      int rg = mt * 256 + r; if (rg > cnt - 1) rg = cnt - 1;                 \
      int gsw = (((tid & 3) ^ (r & 3)) << 3);                                \
      gload_lds16(Xg + (size_t)(off + rg) * HID + (K0) + gsw,                \
                  &sA[P][j * 4096 + tid * 8]);                               \
      int s = r & 63;                                                        \
      int wrow = ntb + ((r >> 6) << 5) + (s & 31);                           \
      const unsigned short* wb = (s < 32) ? b1B : b3B;                       \
      gload_lds16(wb + (size_t)wrow * HID + (K0) + gsw,                      \
                  &sB[P][j * 4096 + tid * 8]);                               \
    }                                                                        \
  } while (0)

  int sl = ((fq ^ (fr & 3)) << 3);   // swizzled granule offset for reads (shorts)

#define COMP1(P)                                                             \
  do {                                                                       \
    short8 bfrag[4];                                                         \
    _Pragma("unroll")                                                        \
    for (int nf = 0; nf < 4; ++nf) {                                         \
      int r = wn * 64 + nf * 16 + fr;                                        \
      bfrag[nf] = *reinterpret_cast<const short8*>(&sB[P][r * 32 + sl]);     \
    }                                                                        \
    _Pragma("unroll")                                                        \
    for (int mf = 0; mf < 8; ++mf) {                                         \
      int r = wm * 128 + mf * 16 + fr;                                       \
      short8 afrag = *reinterpret_cast<const short8*>(&sA[P][r * 32 + sl]);  \
      _Pragma("unroll")                                                      \
      for (int nf = 0; nf < 4; ++nf)                                         \
        acc[mf][nf] = __builtin_amdgcn_mfma_f32_16x16x32_bf16(               \
            afrag, bfrag[nf], acc[mf][nf], 0, 0, 0);                         \
    }                                                                        \
  } while (0)

  STAGE1(0, 0);
  __syncthreads();
  for (int t = 0; t < 32; t += 2) {
    STAGE1(1, (t + 1) * 32);
    COMP1(0);
    __syncthreads();
    if (t + 2 < 32) STAGE1(0, (t + 2) * 32);
    COMP1(1);
    __syncthreads();
  }

#pragma unroll
  for (int mf = 0; mf < 8; ++mf) {
    int rl = wm * 128 + mf * 16 + fq * 4;
#pragma unroll
    for (int jj = 0; jj < 4; ++jj) {
      int gm = mt * 256 + rl + jj;
      if (gm < cnt) {
#pragma unroll
        for (int nf = 0; nf < 2; ++nf) {
          float h1 = acc[mf][nf][jj];
          float h3 = acc[mf][nf + 2][jj];
          float sv = h1 / (1.f + expf(-h1)) * h3;
          int gn = ntb + wn * 32 + nf * 16 + fr;
          hbuf[(size_t)(off + gm) * FFNDIM + gn] = f2bf(sv);
        }
      }
    }
  }
#undef STAGE1
#undef COMP1
}

// ======== GEMM2: 256x256 tile, BK=32, split-K=4, atomic scatter-add epilogue ========
__global__ __launch_bounds__(512, 2) void gemm2_256(
    const unsigned short* __restrict__ hbuf, const unsigned short* __restrict__ Wb2,
    const int* __restrict__ counts, const int* __restrict__ offsets,
    const int* __restrict__ row_tok, const float* __restrict__ row_w,
    float* __restrict__ out) {
  int zz = blockIdx.z;
  int e = zz & 7, kz = zz >> 3;
  int cnt = counts[e];
  int nt = blockIdx.x, mt = blockIdx.y;
  if (cnt == 0 || mt * 256 >= cnt) return;
  int off = offsets[e];
  int kbase = kz * (FFNDIM / 4);

  __shared__ alignas(16) unsigned short sA[2][256 * 32];
  __shared__ alignas(16) unsigned short sB[2][256 * 32];

  int tid = threadIdx.x;
  int lane = tid & 63, wid = tid >> 6;
  int wm = wid >> 2, wn = wid & 3;
  int fr = lane & 15, fq = lane >> 4;

  const unsigned short* bB = Wb2 + (size_t)e * HID * FFNDIM + (size_t)(nt * 256) * FFNDIM;

  f32x4 acc[8][4];
#pragma unroll
  for (int mf = 0; mf < 8; ++mf)
#pragma unroll
    for (int nf = 0; nf < 4; ++nf) acc[mf][nf] = (f32x4){0.f, 0.f, 0.f, 0.f};

#define STAGE2(P, K0)                                                        \
  do {                                                                       \
    _Pragma("unroll")                                                        \
    for (int j = 0; j < 2; ++j) {                                            \
      int r = j * 128 + (tid >> 2);                                          \
      int rg = mt * 256 + r; if (rg > cnt - 1) rg = cnt - 1;                 \
      int gsw = (((tid & 3) ^ (r & 3)) << 3);                                \
      gload_lds16(hbuf + (size_t)(off + rg) * FFNDIM + (K0) + gsw,           \
                  &sA[P][j * 4096 + tid * 8]);                               \
      gload_lds16(bB + (size_t)r * FFNDIM + (K0) + gsw,                      \
                  &sB[P][j * 4096 + tid * 8]);                               \
    }                                                                        \
  } while (0)

  int sl = ((fq ^ (fr & 3)) << 3);

#define COMP2(P)                                                             \
  do {                                                                       \
    short8 bfrag[4];                                                         \
    _Pragma("unroll")                                                        \
    for (int nf = 0; nf < 4; ++nf) {                                         \
      int r = wn * 64 + nf * 16 + fr;                                        \
      bfrag[nf] = *reinterpret_cast<const short8*>(&sB[P][r * 32 + sl]);     \
    }                                                                        \
    _Pragma("unroll")                                                        \
    for (int mf = 0; mf < 8; ++mf) {                                         \
      int r = wm * 128 + mf * 16 + fr;                                       \
      short8 afrag = *reinterpret_cast<const short8*>(&sA[P][r * 32 + sl]);  \
      _Pragma("unroll")                                                      \
      for (int nf = 0; nf < 4; ++nf)                                         \
        acc[mf][nf] = __builtin_amdgcn_mfma_f32_16x16x32_bf16(               \
            afrag, bfrag[nf], acc[mf][nf], 0, 0, 0);                         \
    }                                                                        \
  } while (0)

  STAGE2(0, kbase);
  __syncthreads();
  for (int t = 0; t < 16; t += 2) {
    STAGE2(1, kbase + (t + 1) * 32);
    COMP2(0);
    __syncthreads();
    if (t + 2 < 16) STAGE2(0, kbase + (t + 2) * 32);
    COMP2(1);
    __syncthreads();
  }

#pragma unroll
  for (int mf = 0; mf < 8; ++mf) {
    int rl = wm * 128 + mf * 16 + fq * 4;
#pragma unroll
    for (int jj = 0; jj < 4; ++jj) {
      int gm = mt * 256 + rl + jj;
      if (gm < cnt) {
        int tok = row_tok[off + gm];
        float rw = row_w[off + gm];
#pragma unroll
        for (int nf = 0; nf < 4; ++nf) {
          int gn = nt * 256 + wn * 64 + nf * 16 + fr;
          atomicAdd(&out[(size_t)tok * HID + gn], acc[mf][nf][jj] * rw);
        }
      }
    }
  }
#undef STAGE2
#undef COMP2
}

extern "C" void kernel_launch(void* const* d_in, const int* in_sizes, int n_in,
                              void* d_out, int out_size, void* d_ws, size_t ws_size,
                              hipStream_t stream) {
  const float* x  = (const float*)d_in[0];
  const float* gw = (const float*)d_in[1];
  const float* w1 = (const float*)d_in[2];
  const float* w3 = (const float*)d_in[3];
  const float* w2 = (const float*)d_in[4];
  float* out = (float*)d_out;

  char* ws = (char*)d_ws;
  int*   counts  = (int*)(ws + 0);
  int*   cursor  = (int*)(ws + 32);
  int*   offsets = (int*)(ws + 64);
  int*   top_i   = (int*)(ws + 1024);
  float* top_w   = (float*)(ws + 17408);
  int*   row_tok = (int*)(ws + 33792);
  float* row_w   = (float*)(ws + 50176);
  unsigned short* Xg   = (unsigned short*)(ws + 66560);     // (4096+128)*1024 bf16
  unsigned short* hbuf = (unsigned short*)(ws + 8717312);   // (4096+128)*2048 bf16
  unsigned short* Wb1  = (unsigned short*)(ws + 26018816);  // 32 MB
  unsigned short* Wb3  = (unsigned short*)(ws + 59573248);  // 32 MB
  unsigned short* Wb2  = (unsigned short*)(ws + 93127680);  // 32 MB

  hipMemsetAsync(ws, 0, 128, stream);
  hipMemsetAsync(d_out, 0, (size_t)out_size * sizeof(float), stream);

  router_kernel<<<T_TOK / 4, 256, 0, stream>>>(x, gw, counts, top_i, top_w);
  offsets_kernel<<<1, 64, 0, stream>>>(counts, offsets);
  scatter_kernel<<<(T_TOK + 255) / 256, 256, 0, stream>>>(top_i, top_w, offsets, cursor, row_tok, row_w);
  gather_kernel<<<T_TOK * 2, 256, 0, stream>>>(x, row_tok, Xg);

  const int n4 = NEXP * FFNDIM * HID / 4;
  w2bf3_kernel<<<dim3(n4 / 256, 3), 256, 0, stream>>>(
      (const float4*)w1, (const float4*)w3, (const float4*)w2,
      (ushort4*)Wb1, (ushort4*)Wb3, (ushort4*)Wb2, n4);

  // gemm1: nt fastest (16 tiles of 128 ffn-cols), mt up to 16, e
  gemm1_256<<<dim3(FFNDIM / 128, 16, NEXP), 512, 0, stream>>>(Xg, Wb1, Wb3, counts, offsets, hbuf);
  // gemm2: nt (4 tiles of 256 hid-cols), mt up to 16, e + 4-way split-K
  gemm2_256<<<dim3(HID / 256, 16, NEXP * 4), 512, 0, stream>>>(hbuf, Wb2, counts, offsets, row_tok, row_w, out);
}

// Round 5
// 272.471 us; speedup vs baseline: 1.3580x; 1.3580x over previous
//
#include <hip/hip_runtime.h>
#include <hip/hip_bf16.h>

#define T_TOK 2048
#define HID 1024
#define FFNDIM 2048
#define NEXP 8
#define RPADDED 4224            // 4096 rows + 128 pad
#define YPSTR (RPADDED * HID)   // floats per Y partial plane

typedef __attribute__((ext_vector_type(8))) short short8;
typedef __attribute__((ext_vector_type(4))) float f32x4;

__device__ inline unsigned short f2bf(float f) {
  union { float f; unsigned int u; } v; v.f = f;
  unsigned int u = v.u;
  unsigned int r = (u + 0x7fffu + ((u >> 16) & 1u)) >> 16;
  return (unsigned short)r;
}

__device__ inline short8 pack8(float4 a, float4 b) {
  short8 r;
  r[0] = (short)f2bf(a.x); r[1] = (short)f2bf(a.y);
  r[2] = (short)f2bf(a.z); r[3] = (short)f2bf(a.w);
  r[4] = (short)f2bf(b.x); r[5] = (short)f2bf(b.y);
  r[6] = (short)f2bf(b.z); r[7] = (short)f2bf(b.w);
  return r;
}

__device__ inline void gload_lds16(const void* g, void* l) {
  __builtin_amdgcn_global_load_lds((const __attribute__((address_space(1))) void*)g,
                                   (__attribute__((address_space(3))) void*)l, 16, 0, 0);
}

// ---------------- router: 1 wave per token ----------------
__global__ __launch_bounds__(256) void router_kernel(
    const float* __restrict__ x, const float* __restrict__ gw,
    int* __restrict__ counts, int* __restrict__ top_i, float* __restrict__ top_w) {
  int lane = threadIdx.x & 63;
  int t = blockIdx.x * 4 + (threadIdx.x >> 6);
  if (t >= T_TOK) return;
  float xv[16];
#pragma unroll
  for (int i = 0; i < 16; ++i) xv[i] = x[(size_t)t * HID + i * 64 + lane];
  float logit[NEXP];
#pragma unroll
  for (int e = 0; e < NEXP; ++e) {
    float s = 0.f;
#pragma unroll
    for (int i = 0; i < 16; ++i) s += xv[i] * gw[e * HID + i * 64 + lane];
#pragma unroll
    for (int off = 32; off > 0; off >>= 1) s += __shfl_xor(s, off);
    logit[e] = s;
  }
  if (lane == 0) {
    float mx = logit[0];
#pragma unroll
    for (int e = 1; e < NEXP; ++e) mx = fmaxf(mx, logit[e]);
    float p[NEXP]; float sum = 0.f;
#pragma unroll
    for (int e = 0; e < NEXP; ++e) { p[e] = expf(logit[e] - mx); sum += p[e]; }
#pragma unroll
    for (int e = 0; e < NEXP; ++e) p[e] /= sum;
    int i0 = 0;
#pragma unroll
    for (int e = 1; e < NEXP; ++e) if (p[e] > p[i0]) i0 = e;
    int i1 = (i0 == 0) ? 1 : 0;
#pragma unroll
    for (int e = 0; e < NEXP; ++e) if (e != i0 && p[e] > p[i1]) i1 = e;
    float w0 = p[i0], w1v = p[i1];
    float s2 = w0 + w1v;
    w0 /= s2; w1v /= s2;
    top_i[t * 2 + 0] = i0; top_i[t * 2 + 1] = i1;
    top_w[t * 2 + 0] = w0; top_w[t * 2 + 1] = w1v;
    atomicAdd(&counts[i0], 1);
    atomicAdd(&counts[i1], 1);
  }
}

__global__ void offsets_kernel(const int* __restrict__ counts, int* __restrict__ offsets) {
  if (threadIdx.x == 0 && blockIdx.x == 0) {
    int s = 0;
    for (int e = 0; e < NEXP; ++e) { offsets[e] = s; s += counts[e]; }
    offsets[NEXP] = s;
  }
}

__global__ __launch_bounds__(256) void scatter_kernel(
    const int* __restrict__ top_i, const float* __restrict__ top_w,
    const int* __restrict__ offsets, int* __restrict__ cursor,
    int* __restrict__ row_tok, int* __restrict__ tok_rows) {
  int t = blockIdx.x * 256 + threadIdx.x;
  if (t >= T_TOK) return;
#pragma unroll
  for (int k = 0; k < 2; ++k) {
    int e = top_i[t * 2 + k];
    int p = atomicAdd(&cursor[e], 1);
    int idx = offsets[e] + p;
    row_tok[idx] = t;
    tok_rows[t * 2 + k] = idx;
  }
}

__global__ __launch_bounds__(256) void gather_kernel(
    const float* __restrict__ x, const int* __restrict__ row_tok,
    unsigned short* __restrict__ Xg) {
  int r = blockIdx.x;
  int t = row_tok[r];
  int c = threadIdx.x * 4;
  float4 v = *reinterpret_cast<const float4*>(x + (size_t)t * HID + c);
  ushort4 o;
  o.x = f2bf(v.x); o.y = f2bf(v.y); o.z = f2bf(v.z); o.w = f2bf(v.w);
  *reinterpret_cast<ushort4*>(Xg + (size_t)r * HID + c) = o;
}

// ======== GEMM1: 128 rows x 128 ffn-cols x {w1,w3}; 4 waves; BK=32; reg-staged B ========
__global__ __launch_bounds__(256, 2) void gemm1_rs(
    const unsigned short* __restrict__ Xg,
    const float* __restrict__ w1, const float* __restrict__ w3,
    const int* __restrict__ counts, const int* __restrict__ offsets,
    unsigned short* __restrict__ hbuf) {
  int e = blockIdx.z;
  int cnt = counts[e];
  int nt = blockIdx.x, mt = blockIdx.y;
  if (mt * 128 >= cnt) return;
  int off = offsets[e];

  __shared__ alignas(16) unsigned short sA[2][128 * 32];
  __shared__ alignas(16) unsigned short sB1[2][128 * 32];
  __shared__ alignas(16) unsigned short sB3[2][128 * 32];

  int tid = threadIdx.x;
  int lane = tid & 63, wid = tid >> 6;
  int wm = wid >> 1, wn = wid & 1;
  int fr = lane & 15, fq = lane >> 4;
  int ntb = nt * 128;

  // A staging (global_load_lds): linear LDS dest, pre-swizzled global source
  int rsub = lane >> 2;
  int csw = (((lane & 3) ^ (rsub & 3)) << 3);
  size_t aro0 = (size_t)(wid * 16 + rsub) * HID + csw;
  size_t aro1 = aro0 + (size_t)64 * HID;
  int ald0 = (wid * 16) * 32;
  int ald1 = ald0 + 64 * 32;
  const unsigned short* aB = Xg + (size_t)(off + mt * 128) * HID;

  // B reg-staging geometry: thread covers rows br0 and br0+64, granule bg of 8 fp32
  int br0 = tid >> 2;
  int bg = tid & 3;
  const float* w1e = w1 + (size_t)e * FFNDIM * HID + (size_t)(ntb + br0) * HID + bg * 8;
  const float* w3e = w3 + (size_t)e * FFNDIM * HID + (size_t)(ntb + br0) * HID + bg * 8;
  int bws0 = br0 * 32 + ((bg ^ (br0 & 3)) << 3);
  int bws1 = bws0 + 64 * 32;

  f32x4 acc1[4][4], acc3[4][4];
#pragma unroll
  for (int m = 0; m < 4; ++m)
#pragma unroll
    for (int n = 0; n < 4; ++n) {
      acc1[m][n] = (f32x4){0.f, 0.f, 0.f, 0.f};
      acc3[m][n] = (f32x4){0.f, 0.f, 0.f, 0.f};
    }

  float4 l10, l11, l30, l31, m10, m11, m30, m31;

#define BLOAD1(K0)                                                     \
  do {                                                                 \
    const float* p1 = w1e + (K0);                                      \
    const float* p3 = w3e + (K0);                                      \
    l10 = *(const float4*)p1; l11 = *(const float4*)(p1 + 4);          \
    l30 = *(const float4*)p3; l31 = *(const float4*)(p3 + 4);          \
    const float* q1 = p1 + (size_t)64 * HID;                           \
    const float* q3 = p3 + (size_t)64 * HID;                           \
    m10 = *(const float4*)q1; m11 = *(const float4*)(q1 + 4);          \
    m30 = *(const float4*)q3; m31 = *(const float4*)(q3 + 4);          \
  } while (0)

#define BWRITE1(P)                                                     \
  do {                                                                 \
    *reinterpret_cast<short8*>(&sB1[P][bws0]) = pack8(l10, l11);       \
    *reinterpret_cast<short8*>(&sB3[P][bws0]) = pack8(l30, l31);       \
    *reinterpret_cast<short8*>(&sB1[P][bws1]) = pack8(m10, m11);       \
    *reinterpret_cast<short8*>(&sB3[P][bws1]) = pack8(m30, m31);       \
  } while (0)

#define ASTAGE1(P, K0)                                                 \
  do {                                                                 \
    gload_lds16(aB + aro0 + (K0), &sA[P][ald0]);                       \
    gload_lds16(aB + aro1 + (K0), &sA[P][ald1]);                       \
  } while (0)

  int sl = ((fq ^ (fr & 3)) << 3);

#define COMP1(P)                                                                  \
  do {                                                                            \
    short8 a[4], f1[4], f3[4];                                                    \
    _Pragma("unroll")                                                             \
    for (int m = 0; m < 4; ++m)                                                   \
      a[m] = *reinterpret_cast<const short8*>(&sA[P][(wm * 64 + m * 16 + fr) * 32 + sl]); \
    _Pragma("unroll")                                                             \
    for (int n = 0; n < 4; ++n) {                                                 \
      f1[n] = *reinterpret_cast<const short8*>(&sB1[P][(wn * 64 + n * 16 + fr) * 32 + sl]); \
      f3[n] = *reinterpret_cast<const short8*>(&sB3[P][(wn * 64 + n * 16 + fr) * 32 + sl]); \
    }                                                                             \
    _Pragma("unroll")                                                             \
    for (int m = 0; m < 4; ++m)                                                   \
      _Pragma("unroll")                                                           \
      for (int n = 0; n < 4; ++n) {                                               \
        acc1[m][n] = __builtin_amdgcn_mfma_f32_16x16x32_bf16(a[m], f1[n], acc1[m][n], 0, 0, 0); \
        acc3[m][n] = __builtin_amdgcn_mfma_f32_16x16x32_bf16(a[m], f3[n], acc3[m][n], 0, 0, 0); \
      }                                                                           \
  } while (0)

  // prologue
  BLOAD1(0);
  ASTAGE1(0, 0);
  BWRITE1(0);
  __syncthreads();

  int cur = 0;
  for (int t = 0; t < 32; ++t) {
    int nxt = cur ^ 1;
    if (t < 31) {
      BLOAD1((t + 1) * 32);      // fp32 B -> regs (latency hides under COMP)
      ASTAGE1(nxt, (t + 1) * 32);
    }
    COMP1(cur);
    if (t < 31) BWRITE1(nxt);    // cvt + swizzled ds_write
    __syncthreads();             // drains vm (A dma) + lgkm (B writes)
    cur = nxt;
  }

#pragma unroll
  for (int m = 0; m < 4; ++m) {
    int rl = wm * 64 + m * 16 + fq * 4;
#pragma unroll
    for (int jj = 0; jj < 4; ++jj) {
      int gm = mt * 128 + rl + jj;
      if (gm < cnt) {
#pragma unroll
        for (int n = 0; n < 4; ++n) {
          float h1 = acc1[m][n][jj], h3 = acc3[m][n][jj];
          float sv = h1 / (1.f + expf(-h1)) * h3;
          int gn = ntb + wn * 64 + n * 16 + fr;
          hbuf[(size_t)(off + gm) * FFNDIM + gn] = f2bf(sv);
        }
      }
    }
  }
#undef BLOAD1
#undef BWRITE1
#undef ASTAGE1
#undef COMP1
}

// ======== GEMM2: 128x128 tile; split-K=2 -> Y partial planes (no atomics) ========
__global__ __launch_bounds__(256, 2) void gemm2_rs(
    const unsigned short* __restrict__ hbuf, const float* __restrict__ w2,
    const int* __restrict__ counts, const int* __restrict__ offsets,
    float* __restrict__ Yg) {
  int zz = blockIdx.z;
  int e = zz & 7, kz = zz >> 3;
  int cnt = counts[e];
  int nt = blockIdx.x, mt = blockIdx.y;
  if (mt * 128 >= cnt) return;
  int off = offsets[e];
  int kbase = kz * (FFNDIM / 2);

  __shared__ alignas(16) unsigned short sA[2][128 * 32];
  __shared__ alignas(16) unsigned short sB[2][128 * 32];

  int tid = threadIdx.x;
  int lane = tid & 63, wid = tid >> 6;
  int wm = wid >> 1, wn = wid & 1;
  int fr = lane & 15, fq = lane >> 4;
  int ntb = nt * 128;

  int rsub = lane >> 2;
  int csw = (((lane & 3) ^ (rsub & 3)) << 3);
  size_t aro0 = (size_t)(wid * 16 + rsub) * FFNDIM + kbase + csw;
  size_t aro1 = aro0 + (size_t)64 * FFNDIM;
  int ald0 = (wid * 16) * 32;
  int ald1 = ald0 + 64 * 32;
  const unsigned short* aB = hbuf + (size_t)(off + mt * 128) * FFNDIM;

  int br0 = tid >> 2;
  int bg = tid & 3;
  const float* w2e = w2 + (size_t)e * HID * FFNDIM + (size_t)(ntb + br0) * FFNDIM + kbase + bg * 8;
  int bws0 = br0 * 32 + ((bg ^ (br0 & 3)) << 3);
  int bws1 = bws0 + 64 * 32;

  f32x4 acc[4][4];
#pragma unroll
  for (int m = 0; m < 4; ++m)
#pragma unroll
    for (int n = 0; n < 4; ++n) acc[m][n] = (f32x4){0.f, 0.f, 0.f, 0.f};

  float4 l0, l1, m0, m1;

#define BLOAD2(K0)                                                     \
  do {                                                                 \
    const float* p = w2e + (K0);                                       \
    l0 = *(const float4*)p; l1 = *(const float4*)(p + 4);              \
    const float* q = p + (size_t)64 * FFNDIM;                          \
    m0 = *(const float4*)q; m1 = *(const float4*)(q + 4);              \
  } while (0)

#define BWRITE2(P)                                                     \
  do {                                                                 \
    *reinterpret_cast<short8*>(&sB[P][bws0]) = pack8(l0, l1);          \
    *reinterpret_cast<short8*>(&sB[P][bws1]) = pack8(m0, m1);          \
  } while (0)

#define ASTAGE2(P, K0)                                                 \
  do {                                                                 \
    gload_lds16(aB + aro0 + (K0), &sA[P][ald0]);                       \
    gload_lds16(aB + aro1 + (K0), &sA[P][ald1]);                       \
  } while (0)

  int sl = ((fq ^ (fr & 3)) << 3);

#define COMP2(P)                                                                  \
  do {                                                                            \
    short8 a[4], b[4];                                                            \
    _Pragma("unroll")                                                             \
    for (int m = 0; m < 4; ++m)                                                   \
      a[m] = *reinterpret_cast<const short8*>(&sA[P][(wm * 64 + m * 16 + fr) * 32 + sl]); \
    _Pragma("unroll")                                                             \
    for (int n = 0; n < 4; ++n)                                                   \
      b[n] = *reinterpret_cast<const short8*>(&sB[P][(wn * 64 + n * 16 + fr) * 32 + sl]); \
    _Pragma("unroll")                                                             \
    for (int m = 0; m < 4; ++m)                                                   \
      _Pragma("unroll")                                                           \
      for (int n = 0; n < 4; ++n)                                                 \
        acc[m][n] = __builtin_amdgcn_mfma_f32_16x16x32_bf16(a[m], b[n], acc[m][n], 0, 0, 0); \
  } while (0)

  BLOAD2(0);
  ASTAGE2(0, 0);
  BWRITE2(0);
  __syncthreads();

  int cur = 0;
  for (int t = 0; t < 32; ++t) {
    int nxt = cur ^ 1;
    if (t < 31) {
      BLOAD2((t + 1) * 32);
      ASTAGE2(nxt, (t + 1) * 32);
    }
    COMP2(cur);
    if (t < 31) BWRITE2(nxt);
    __syncthreads();
    cur = nxt;
  }

  float* yp = Yg + (size_t)kz * YPSTR;
#pragma unroll
  for (int m = 0; m < 4; ++m) {
    int rl = wm * 64 + m * 16 + fq * 4;
#pragma unroll
    for (int jj = 0; jj < 4; ++jj) {
      int gm = mt * 128 + rl + jj;
      if (gm < cnt) {
#pragma unroll
        for (int n = 0; n < 4; ++n) {
          int gn = ntb + wn * 64 + n * 16 + fr;
          yp[(size_t)(off + gm) * HID + gn] = acc[m][n][jj];
        }
      }
    }
  }
#undef BLOAD2
#undef BWRITE2
#undef ASTAGE2
#undef COMP2
}

// ======== combine: out[t] = tw0*(Y0[r0]+Y1[r0]) + tw1*(Y0[r1]+Y1[r1]) ========
__global__ __launch_bounds__(256) void combine_kernel(
    const float* __restrict__ Yg, const int* __restrict__ tok_rows,
    const float* __restrict__ top_w, float* __restrict__ out) {
  int t = blockIdx.x;
  int c = threadIdx.x * 4;
  int r0 = tok_rows[t * 2 + 0];
  int r1 = tok_rows[t * 2 + 1];
  float tw0 = top_w[t * 2 + 0];
  float tw1 = top_w[t * 2 + 1];
  const float* Y0 = Yg;
  const float* Y1 = Yg + (size_t)YPSTR;
  float4 a0 = *reinterpret_cast<const float4*>(Y0 + (size_t)r0 * HID + c);
  float4 b0 = *reinterpret_cast<const float4*>(Y1 + (size_t)r0 * HID + c);
  float4 a1 = *reinterpret_cast<const float4*>(Y0 + (size_t)r1 * HID + c);
  float4 b1 = *reinterpret_cast<const float4*>(Y1 + (size_t)r1 * HID + c);
  float4 o;
  o.x = tw0 * (a0.x + b0.x) + tw1 * (a1.x + b1.x);
  o.y = tw0 * (a0.y + b0.y) + tw1 * (a1.y + b1.y);
  o.z = tw0 * (a0.z + b0.z) + tw1 * (a1.z + b1.z);
  o.w = tw0 * (a0.w + b0.w) + tw1 * (a1.w + b1.w);
  *reinterpret_cast<float4*>(out + (size_t)t * HID + c) = o;
}

extern "C" void kernel_launch(void* const* d_in, const int* in_sizes, int n_in,
                              void* d_out, int out_size, void* d_ws, size_t ws_size,
                              hipStream_t stream) {
  const float* x  = (const float*)d_in[0];
  const float* gw = (const float*)d_in[1];
  const float* w1 = (const float*)d_in[2];
  const float* w3 = (const float*)d_in[3];
  const float* w2 = (const float*)d_in[4];
  float* out = (float*)d_out;

  char* ws = (char*)d_ws;
  int*   counts   = (int*)(ws + 0);
  int*   cursor   = (int*)(ws + 32);
  int*   offsets  = (int*)(ws + 64);
  int*   top_i    = (int*)(ws + 1024);       // 16 KB
  float* top_w    = (float*)(ws + 17408);    // 16 KB
  int*   row_tok  = (int*)(ws + 33792);      // 16 KB
  int*   tok_rows = (int*)(ws + 50176);      // 16 KB
  unsigned short* Xg   = (unsigned short*)(ws + 66560);     // 4224*1024 bf16 = 8.65 MB
  unsigned short* hbuf = (unsigned short*)(ws + 8717312);   // 4224*2048 bf16 = 17.3 MB
  float*          Yg   = (float*)(ws + 26018816);           // 2*4224*1024 f32 = 34.6 MB

  hipMemsetAsync(ws, 0, 128, stream);

  router_kernel<<<T_TOK / 4, 256, 0, stream>>>(x, gw, counts, top_i, top_w);
  offsets_kernel<<<1, 64, 0, stream>>>(counts, offsets);
  scatter_kernel<<<(T_TOK + 255) / 256, 256, 0, stream>>>(top_i, top_w, offsets, cursor, row_tok, tok_rows);
  gather_kernel<<<T_TOK * 2, 256, 0, stream>>>(x, row_tok, Xg);

  // gemm1: nt fastest (16 tiles of 128 ffn-cols) -> XCD-balanced; mt up to 16; e
  gemm1_rs<<<dim3(FFNDIM / 128, 16, NEXP), 256, 0, stream>>>(Xg, w1, w3, counts, offsets, hbuf);
  // gemm2: nt (8 tiles of 128 hid-cols); mt up to 16; e + 2-way split-K
  gemm2_rs<<<dim3(HID / 128, 16, NEXP * 2), 256, 0, stream>>>(hbuf, w2, counts, offsets, Yg);
  combine_kernel<<<T_TOK, 256, 0, stream>>>(Yg, tok_rows, top_w, out);
}

// Round 6
// 250.029 us; speedup vs baseline: 1.4799x; 1.0898x over previous
//
#include <hip/hip_runtime.h>
#include <hip/hip_bf16.h>

#define T_TOK 2048
#define HID 1024
#define FFNDIM 2048
#define NEXP 8
#define RPADDED 4224
#define YPSTR (RPADDED * HID)

typedef __attribute__((ext_vector_type(8))) short short8;
typedef __attribute__((ext_vector_type(4))) float f32x4;

__device__ inline unsigned short f2bf(float f) {
  union { float f; unsigned int u; } v; v.f = f;
  unsigned int u = v.u;
  unsigned int r = (u + 0x7fffu + ((u >> 16) & 1u)) >> 16;
  return (unsigned short)r;
}

__device__ inline short8 pack8(float4 a, float4 b) {
  short8 r;
  r[0] = (short)f2bf(a.x); r[1] = (short)f2bf(a.y);
  r[2] = (short)f2bf(a.z); r[3] = (short)f2bf(a.w);
  r[4] = (short)f2bf(b.x); r[5] = (short)f2bf(b.y);
  r[6] = (short)f2bf(b.z); r[7] = (short)f2bf(b.w);
  return r;
}

__device__ inline void gload_lds16(const void* g, void* l) {
  __builtin_amdgcn_global_load_lds((const __attribute__((address_space(1))) void*)g,
                                   (__attribute__((address_space(3))) void*)l, 16, 0, 0);
}

// ---------------- router ----------------
__global__ __launch_bounds__(256) void router_kernel(
    const float* __restrict__ x, const float* __restrict__ gw,
    int* __restrict__ counts, int* __restrict__ top_i, float* __restrict__ top_w) {
  int lane = threadIdx.x & 63;
  int t = blockIdx.x * 4 + (threadIdx.x >> 6);
  if (t >= T_TOK) return;
  float xv[16];
#pragma unroll
  for (int i = 0; i < 16; ++i) xv[i] = x[(size_t)t * HID + i * 64 + lane];
  float logit[NEXP];
#pragma unroll
  for (int e = 0; e < NEXP; ++e) {
    float s = 0.f;
#pragma unroll
    for (int i = 0; i < 16; ++i) s += xv[i] * gw[e * HID + i * 64 + lane];
#pragma unroll
    for (int off = 32; off > 0; off >>= 1) s += __shfl_xor(s, off);
    logit[e] = s;
  }
  if (lane == 0) {
    float mx = logit[0];
#pragma unroll
    for (int e = 1; e < NEXP; ++e) mx = fmaxf(mx, logit[e]);
    float p[NEXP]; float sum = 0.f;
#pragma unroll
    for (int e = 0; e < NEXP; ++e) { p[e] = expf(logit[e] - mx); sum += p[e]; }
#pragma unroll
    for (int e = 0; e < NEXP; ++e) p[e] /= sum;
    int i0 = 0;
#pragma unroll
    for (int e = 1; e < NEXP; ++e) if (p[e] > p[i0]) i0 = e;
    int i1 = (i0 == 0) ? 1 : 0;
#pragma unroll
    for (int e = 0; e < NEXP; ++e) if (e != i0 && p[e] > p[i1]) i1 = e;
    float w0 = p[i0], w1v = p[i1];
    float s2 = w0 + w1v;
    w0 /= s2; w1v /= s2;
    top_i[t * 2 + 0] = i0; top_i[t * 2 + 1] = i1;
    top_w[t * 2 + 0] = w0; top_w[t * 2 + 1] = w1v;
    atomicAdd(&counts[i0], 1);
    atomicAdd(&counts[i1], 1);
  }
}

__global__ void offsets_kernel(const int* __restrict__ counts, int* __restrict__ offsets) {
  if (threadIdx.x == 0 && blockIdx.x == 0) {
    int s = 0;
    for (int e = 0; e < NEXP; ++e) { offsets[e] = s; s += counts[e]; }
    offsets[NEXP] = s;
  }
}

__global__ __launch_bounds__(256) void scatter_kernel(
    const int* __restrict__ top_i, const float* __restrict__ top_w,
    const int* __restrict__ offsets, int* __restrict__ cursor,
    int* __restrict__ row_tok, int* __restrict__ tok_rows) {
  int t = blockIdx.x * 256 + threadIdx.x;
  if (t >= T_TOK) return;
#pragma unroll
  for (int k = 0; k < 2; ++k) {
    int e = top_i[t * 2 + k];
    int p = atomicAdd(&cursor[e], 1);
    int idx = offsets[e] + p;
    row_tok[idx] = t;
    tok_rows[t * 2 + k] = idx;
  }
}

__global__ __launch_bounds__(256) void gather_kernel(
    const float* __restrict__ x, const int* __restrict__ row_tok,
    unsigned short* __restrict__ Xg) {
  int r = blockIdx.x;
  int t = row_tok[r];
  int c = threadIdx.x * 4;
  float4 v = *reinterpret_cast<const float4*>(x + (size_t)t * HID + c);
  ushort4 o;
  o.x = f2bf(v.x); o.y = f2bf(v.y); o.z = f2bf(v.z); o.w = f2bf(v.w);
  *reinterpret_cast<ushort4*>(Xg + (size_t)r * HID + c) = o;
}

// ======== GEMM1: BM=256 rows x 32 ffn-cols (w1+w3); 4 waves; BK=32 ========
// B tile: 64 rows x 32 K: rows 0-31 = w1 cols ntb+0..31, rows 32-63 = w3 cols ntb+0..31.
// Wave wm: out rows wm*64 + mf*16; frags nf: 0,1 -> w1 cols nf*16+fr; 2,3 -> w3.
__global__ __launch_bounds__(256, 3) void gemm1_v6(
    const unsigned short* __restrict__ Xg,
    const float* __restrict__ w1, const float* __restrict__ w3,
    const int* __restrict__ counts, const int* __restrict__ offsets,
    unsigned short* __restrict__ hbuf) {
  int e = blockIdx.z;
  int cnt = counts[e];
  int nt = blockIdx.x, mt = blockIdx.y;
  if (cnt == 0 || mt * 256 >= cnt) return;
  int off = offsets[e];
  int ntb = nt * 32;

  __shared__ alignas(16) unsigned short sA[2][256 * 32];
  __shared__ alignas(16) unsigned short sB[2][64 * 32];

  int tid = threadIdx.x;
  int lane = tid & 63, wid = tid >> 6;
  int wm = wid;                       // 4 waves, pure M split
  int fr = lane & 15, fq = lane >> 4;

  // ---- A staging (global_load_lds, 4 issues of 4KB) ----
  size_t asrc[4];
#pragma unroll
  for (int j = 0; j < 4; ++j) {
    int r = j * 64 + wid * 16 + (lane >> 2);
    int rg = mt * 256 + r; if (rg > cnt - 1) rg = cnt - 1;
    int gsw = ((lane & 3) ^ (r & 3)) << 3;
    asrc[j] = (size_t)(off + rg) * HID + gsw;
  }
#define ASTAGE(P, K0)                                                      \
  do {                                                                     \
    _Pragma("unroll")                                                      \
    for (int j = 0; j < 4; ++j)                                            \
      gload_lds16(Xg + asrc[j] + (K0), &sA[P][j * 2048 + wid * 512]);      \
  } while (0)

  // ---- B staging: reg-staged fp32, 8 fp32/thread ----
  int rb = tid >> 2;                  // 0..63
  int bg = tid & 3;                   // granule of 8 fp32
  const float* bsrc = (rb < 32)
      ? (w1 + ((size_t)e * FFNDIM + ntb + rb) * HID + bg * 8)
      : (w3 + ((size_t)e * FFNDIM + ntb + rb - 32) * HID + bg * 8);
  int bdst = rb * 32 + ((bg ^ (rb & 3)) << 3);

  float4 pA0, pA1, pB0, pB1;          // two named prefetch sets (rule #20)
#define BLOADA(K0) do { pA0 = *(const float4*)(bsrc + (K0)); pA1 = *(const float4*)(bsrc + (K0) + 4); } while (0)
#define BLOADB(K0) do { pB0 = *(const float4*)(bsrc + (K0)); pB1 = *(const float4*)(bsrc + (K0) + 4); } while (0)
#define BWRITEA(P) do { *reinterpret_cast<short8*>(&sB[P][bdst]) = pack8(pA0, pA1); } while (0)
#define BWRITEB(P) do { *reinterpret_cast<short8*>(&sB[P][bdst]) = pack8(pB0, pB1); } while (0)

  f32x4 acc[4][4];
#pragma unroll
  for (int mf = 0; mf < 4; ++mf)
#pragma unroll
    for (int nf = 0; nf < 4; ++nf) acc[mf][nf] = (f32x4){0.f, 0.f, 0.f, 0.f};

  int sl = ((fq ^ (fr & 3)) << 3);

#define COMP(P)                                                              \
  do {                                                                       \
    short8 b[4];                                                             \
    _Pragma("unroll")                                                        \
    for (int nf = 0; nf < 4; ++nf)                                           \
      b[nf] = *reinterpret_cast<const short8*>(&sB[P][(nf * 16 + fr) * 32 + sl]); \
    _Pragma("unroll")                                                        \
    for (int mf = 0; mf < 4; ++mf) {                                         \
      short8 a = *reinterpret_cast<const short8*>(&sA[P][(wm * 64 + mf * 16 + fr) * 32 + sl]); \
      _Pragma("unroll")                                                      \
      for (int nf = 0; nf < 4; ++nf)                                         \
        acc[mf][nf] = __builtin_amdgcn_mfma_f32_16x16x32_bf16(a, b[nf], acc[mf][nf], 0, 0, 0); \
    }                                                                        \
  } while (0)

  const int NT = HID / 32;            // 32
  // prologue
  BLOADA(0);
  ASTAGE(0, 0);
  BWRITEA(0);
  BLOADA(32);
  BLOADB(64);
  __syncthreads();

  for (int t = 0; t < NT; t += 2) {
    // even: buf0 holds t; pA holds t+1; pB holds t+2
    ASTAGE(1, (t + 1) * 32);
    COMP(0);
    BWRITEA(1);
    if (t + 3 < NT) BLOADA((t + 3) * 32);
    __syncthreads();
    // odd: buf1 holds t+1; pB holds t+2; pA holds t+3
    if (t + 2 < NT) ASTAGE(0, (t + 2) * 32);
    COMP(1);
    if (t + 2 < NT) BWRITEB(0);
    if (t + 4 < NT) BLOADB((t + 4) * 32);
    __syncthreads();
  }

#pragma unroll
  for (int mf = 0; mf < 4; ++mf) {
    int rl = wm * 64 + mf * 16 + fq * 4;
#pragma unroll
    for (int jj = 0; jj < 4; ++jj) {
      int gm = mt * 256 + rl + jj;
      if (gm < cnt) {
#pragma unroll
        for (int nf = 0; nf < 2; ++nf) {
          float h1 = acc[mf][nf][jj];
          float h3 = acc[mf][nf + 2][jj];
          float sv = h1 / (1.f + expf(-h1)) * h3;
          hbuf[(size_t)(off + gm) * FFNDIM + ntb + nf * 16 + fr] = f2bf(sv);
        }
      }
    }
  }
#undef ASTAGE
#undef BLOADA
#undef BLOADB
#undef BWRITEA
#undef BWRITEB
#undef COMP
}

// ======== GEMM2: BM=256 rows x 32 hid-cols; 4 waves; BK=32; K=2048 ========
__global__ __launch_bounds__(256, 4) void gemm2_v6(
    const unsigned short* __restrict__ hbuf, const float* __restrict__ w2,
    const int* __restrict__ counts, const int* __restrict__ offsets,
    float* __restrict__ Yg) {
  int e = blockIdx.z;
  int cnt = counts[e];
  int nt = blockIdx.x, mt = blockIdx.y;
  if (cnt == 0 || mt * 256 >= cnt) return;
  int off = offsets[e];
  int ntb = nt * 32;

  __shared__ alignas(16) unsigned short sA[2][256 * 32];
  __shared__ alignas(16) unsigned short sB[2][32 * 32];

  int tid = threadIdx.x;
  int lane = tid & 63, wid = tid >> 6;
  int wm = wid;
  int fr = lane & 15, fq = lane >> 4;

  size_t asrc[4];
#pragma unroll
  for (int j = 0; j < 4; ++j) {
    int r = j * 64 + wid * 16 + (lane >> 2);
    int rg = mt * 256 + r; if (rg > cnt - 1) rg = cnt - 1;
    int gsw = ((lane & 3) ^ (r & 3)) << 3;
    asrc[j] = (size_t)(off + rg) * FFNDIM + gsw;
  }
#define ASTAGE(P, K0)                                                      \
  do {                                                                     \
    _Pragma("unroll")                                                      \
    for (int j = 0; j < 4; ++j)                                            \
      gload_lds16(hbuf + asrc[j] + (K0), &sA[P][j * 2048 + wid * 512]);    \
  } while (0)

  // B: 32 rows x 32 K fp32 -> 4 fp32/thread
  int rb = tid >> 3;                  // 0..31
  int g4 = tid & 7;                   // granule of 4 fp32 (8B bf16)
  const float* bsrc = w2 + ((size_t)e * HID + ntb + rb) * FFNDIM + g4 * 4;
  int bdst = rb * 32 + ((((g4 >> 1) ^ (rb & 3)) << 3) + ((g4 & 1) << 2));

  float4 pA, pB;
#define BLOADA(K0) do { pA = *(const float4*)(bsrc + (K0)); } while (0)
#define BLOADB(K0) do { pB = *(const float4*)(bsrc + (K0)); } while (0)
#define BWRV(P, V)                                                         \
  do {                                                                     \
    ushort4 o;                                                             \
    o.x = f2bf(V.x); o.y = f2bf(V.y); o.z = f2bf(V.z); o.w = f2bf(V.w);    \
    *reinterpret_cast<ushort4*>(&sB[P][bdst]) = o;                         \
  } while (0)

  f32x4 acc[4][2];
#pragma unroll
  for (int mf = 0; mf < 4; ++mf)
#pragma unroll
    for (int nf = 0; nf < 2; ++nf) acc[mf][nf] = (f32x4){0.f, 0.f, 0.f, 0.f};

  int sl = ((fq ^ (fr & 3)) << 3);

#define COMP(P)                                                              \
  do {                                                                       \
    short8 b[2];                                                             \
    _Pragma("unroll")                                                        \
    for (int nf = 0; nf < 2; ++nf)                                           \
      b[nf] = *reinterpret_cast<const short8*>(&sB[P][(nf * 16 + fr) * 32 + sl]); \
    _Pragma("unroll")                                                        \
    for (int mf = 0; mf < 4; ++mf) {                                         \
      short8 a = *reinterpret_cast<const short8*>(&sA[P][(wm * 64 + mf * 16 + fr) * 32 + sl]); \
      _Pragma("unroll")                                                      \
      for (int nf = 0; nf < 2; ++nf)                                         \
        acc[mf][nf] = __builtin_amdgcn_mfma_f32_16x16x32_bf16(a, b[nf], acc[mf][nf], 0, 0, 0); \
    }                                                                        \
  } while (0)

  const int NT = FFNDIM / 32;         // 64
  BLOADA(0);
  ASTAGE(0, 0);
  BWRV(0, pA);
  BLOADA(32);
  BLOADB(64);
  __syncthreads();

  for (int t = 0; t < NT; t += 2) {
    ASTAGE(1, (t + 1) * 32);
    COMP(0);
    BWRV(1, pA);
    if (t + 3 < NT) BLOADA((t + 3) * 32);
    __syncthreads();
    if (t + 2 < NT) ASTAGE(0, (t + 2) * 32);
    COMP(1);
    if (t + 2 < NT) BWRV(0, pB);
    if (t + 4 < NT) BLOADB((t + 4) * 32);
    __syncthreads();
  }

#pragma unroll
  for (int mf = 0; mf < 4; ++mf) {
    int rl = wm * 64 + mf * 16 + fq * 4;
#pragma unroll
    for (int jj = 0; jj < 4; ++jj) {
      int gm = mt * 256 + rl + jj;
      if (gm < cnt) {
#pragma unroll
        for (int nf = 0; nf < 2; ++nf)
          Yg[(size_t)(off + gm) * HID + ntb + nf * 16 + fr] = acc[mf][nf][jj];
      }
    }
  }
#undef ASTAGE
#undef BLOADA
#undef BLOADB
#undef BWRV
#undef COMP
}

// ======== combine: out[t] = tw0*Y[r0] + tw1*Y[r1] ========
__global__ __launch_bounds__(256) void combine_kernel(
    const float* __restrict__ Yg, const int* __restrict__ tok_rows,
    const float* __restrict__ top_w, float* __restrict__ out) {
  int t = blockIdx.x;
  int c = threadIdx.x * 4;
  int r0 = tok_rows[t * 2 + 0];
  int r1 = tok_rows[t * 2 + 1];
  float tw0 = top_w[t * 2 + 0];
  float tw1 = top_w[t * 2 + 1];
  float4 a0 = *reinterpret_cast<const float4*>(Yg + (size_t)r0 * HID + c);
  float4 a1 = *reinterpret_cast<const float4*>(Yg + (size_t)r1 * HID + c);
  float4 o;
  o.x = tw0 * a0.x + tw1 * a1.x;
  o.y = tw0 * a0.y + tw1 * a1.y;
  o.z = tw0 * a0.z + tw1 * a1.z;
  o.w = tw0 * a0.w + tw1 * a1.w;
  *reinterpret_cast<float4*>(out + (size_t)t * HID + c) = o;
}

extern "C" void kernel_launch(void* const* d_in, const int* in_sizes, int n_in,
                              void* d_out, int out_size, void* d_ws, size_t ws_size,
                              hipStream_t stream) {
  const float* x  = (const float*)d_in[0];
  const float* gw = (const float*)d_in[1];
  const float* w1 = (const float*)d_in[2];
  const float* w3 = (const float*)d_in[3];
  const float* w2 = (const float*)d_in[4];
  float* out = (float*)d_out;

  char* ws = (char*)d_ws;
  int*   counts   = (int*)(ws + 0);
  int*   cursor   = (int*)(ws + 32);
  int*   offsets  = (int*)(ws + 64);
  int*   top_i    = (int*)(ws + 1024);
  float* top_w    = (float*)(ws + 17408);
  int*   row_tok  = (int*)(ws + 33792);
  int*   tok_rows = (int*)(ws + 50176);
  unsigned short* Xg   = (unsigned short*)(ws + 66560);     // 4224*1024 bf16
  unsigned short* hbuf = (unsigned short*)(ws + 8717312);   // 4224*2048 bf16
  float*          Yg   = (float*)(ws + 26018816);           // 4224*1024 f32

  hipMemsetAsync(ws, 0, 128, stream);

  router_kernel<<<T_TOK / 4, 256, 0, stream>>>(x, gw, counts, top_i, top_w);
  offsets_kernel<<<1, 64, 0, stream>>>(counts, offsets);
  scatter_kernel<<<(T_TOK + 255) / 256, 256, 0, stream>>>(top_i, top_w, offsets, cursor, row_tok, tok_rows);
  gather_kernel<<<T_TOK * 2, 256, 0, stream>>>(x, row_tok, Xg);

  // gemm1: 64 n-tiles (32 ffn-cols each), 8 m-tiles (256 rows, safety), 8 experts
  gemm1_v6<<<dim3(FFNDIM / 32, 8, NEXP), 256, 0, stream>>>(Xg, w1, w3, counts, offsets, hbuf);
  // gemm2: 32 n-tiles (32 hid-cols), 8 m-tiles, 8 experts
  gemm2_v6<<<dim3(HID / 32, 8, NEXP), 256, 0, stream>>>(hbuf, w2, counts, offsets, Yg);
  combine_kernel<<<T_TOK, 256, 0, stream>>>(Yg, tok_rows, top_w, out);
}